// Round 6
// baseline (3955.885 us; speedup 1.0000x reference)
//
#include <hip/hip_runtime.h>

// Problem constants
#define H 2048
#define W 2048
#define C 3
#define RAD 5
#define P (H + 2*RAD)           // 2058 padded state dimension
#define RS 2064                 // row stride (16-elem aligned)
#define PLANE ((size_t)P * RS)  // elements per channel plane
#define NITER 10

// Tile config
#define BX 64
#define BY 16
#define EX (BX + 2*RAD)         // 74
#define EY (BY + 2*RAD)         // 26
#define LSTR (EX + 1)           // 75

// ---------------------------------------------------------------------------
// Pad: HWC float32 img -> padded f32 plane(s) (edge replication), z-batched.
// ---------------------------------------------------------------------------
__global__ void pad_kernel(const float* __restrict__ img, float* __restrict__ dst, int c0) {
    int idx = blockIdx.x * blockDim.x + threadIdx.x;
    int total = P * P;
    if (idx >= total) return;
    int c = c0 + blockIdx.z;
    float* d = dst + (size_t)blockIdx.z * PLANE;
    int y = idx / P;
    int x = idx - y * P;
    int ys = min(max(y - RAD, 0), H - 1);
    int xs = min(max(x - RAD, 0), W - 1);
    d[(size_t)y * RS + x] = img[((size_t)ys * W + xs) * C + c];
}

// ---------------------------------------------------------------------------
// One side-window iteration. Per-pixel arithmetic is BIT-EXACTLY round-0's
// verified sequence: taps in row-major (ky,kx) order, each tap contributing
// round(w*u) [scalar __fmul_rn, weight first] then round(acc+p) [scalar
// __fadd_rn] into 8 accumulators [LL,LR,RL,RR,Lk,Rk,kL,kR]; argmin over |d|
// with first-index tie-break; output = __fadd_rn(u, best).
//
// Speed structure (provably bit-preserving — scalar ops only):
//  - Each thread owns 4 ADJACENT rows (r0..r0+3) of one column. Iterating
//    global tap row gr=0..13 with ky = gr - rp visits each pixel's taps in
//    exactly ascending (ky,kx) row-major order (gr outer asc, kx inner asc,
//    rp innermost does not affect any single pixel's chain order).
//  - The tap value and its two off-center products are loaded/computed ONCE
//    per (gr,kx) and shared across the 4 rows: identical pure ops on
//    identical inputs — CSE, bit-identical. LDS reads 121 -> 38.5 per px,
//    muls 242 -> 77 per px. The 408 adds/px (distinct accumulators) and the
//    argmin are untouched.
//  - Fully unrolled: all predicates compile-time (round-0's row loop was
//    `#pragma unroll 1` with runtime predicates).
// ---------------------------------------------------------------------------
__global__ __launch_bounds__(256)
void step_kernel(const float* __restrict__ src, float* __restrict__ dst,
                 const float* __restrict__ kern) {
    __shared__ float sU[EY][LSTR];

    // Exact f32 weights: corner kernels (w36 off-center, c36 center),
    // side kernels (w66 off-center, c66 center).
    const float w36 = kern[0];                    // [0,0,0,0]
    const float c36 = kern[5 * 11 + 5];           // [0,0,5,5]
    const float w66 = kern[4 * 121];              // [4,0,0,0]
    const float c66 = kern[4 * 121 + 5 * 11 + 5];

    const int x0 = blockIdx.x * BX;
    const int y0 = blockIdx.y * BY;
    const float* sp = src + (size_t)blockIdx.z * PLANE;
    float*       dp = dst + (size_t)blockIdx.z * PLANE;
    const int tid = threadIdx.y * 64 + threadIdx.x;   // blockDim = (64,4)

    // Stage tile + halo; outside [0,P) is zero (conv zero padding) — verbatim round-0
    for (int i = tid; i < EY * EX; i += 256) {
        int r   = i / EX;
        int col = i - r * EX;
        int gy = y0 - RAD + r;
        int gx = x0 - RAD + col;
        float v = 0.0f;
        if (gy >= 0 && gy < P && gx >= 0 && gx < P)
            v = sp[(size_t)gy * RS + gx];
        sU[r][col] = v;
    }
    __syncthreads();

    const int tx = threadIdx.x;
    const int gx = x0 + tx;
    const int r0 = threadIdx.y * 4;   // 4 adjacent rows r0..r0+3 (0,4,8,12)

    // acc[rp][j]: all indices compile-time after unroll -> registers (32 VGPR)
    float acc[4][8];
    #pragma unroll
    for (int rp = 0; rp < 4; ++rp)
        #pragma unroll
        for (int j = 0; j < 8; ++j)
            acc[rp][j] = 0.0f;

    #pragma unroll
    for (int gr = 0; gr < 14; ++gr) {
        #pragma unroll
        for (int kx = 0; kx < 11; ++kx) {
            const float uv  = sU[r0 + gr][tx + kx];
            const float p36 = __fmul_rn(w36, uv);   // shared off-center products
            const float p66 = __fmul_rn(w66, uv);
            #pragma unroll
            for (int rp = 0; rp < 4; ++rp) {
                const int ky = gr - rp;            // compile-time
                if (ky < 0 || ky > 10) continue;
                const bool Lv = (ky <= 5), Rv = (ky >= 5);
                const bool Lh = (kx <= 5), Rh = (kx >= 5);
                const bool ctr = (ky == 5) && (kx == 5);
                const float pc = ctr ? __fmul_rn(c36, uv) : p36;
                const float ps = ctr ? __fmul_rn(c66, uv) : p66;
                if (Lv && Lh) acc[rp][0] = __fadd_rn(acc[rp][0], pc);  // LL
                if (Lv && Rh) acc[rp][1] = __fadd_rn(acc[rp][1], pc);  // LR
                if (Rv && Lh) acc[rp][2] = __fadd_rn(acc[rp][2], pc);  // RL
                if (Rv && Rh) acc[rp][3] = __fadd_rn(acc[rp][3], pc);  // RR
                if (Lv)       acc[rp][4] = __fadd_rn(acc[rp][4], ps);  // Lk
                if (Rv)       acc[rp][5] = __fadd_rn(acc[rp][5], ps);  // Rk
                if (Lh)       acc[rp][6] = __fadd_rn(acc[rp][6], ps);  // kL
                if (Rh)       acc[rp][7] = __fadd_rn(acc[rp][7], ps);  // kR
            }
        }
    }

    // Epilogue: verbatim round-0 argmin per pixel
    #pragma unroll
    for (int rp = 0; rp < 4; ++rp) {
        const int gy = y0 + r0 + rp;
        if (gx >= P || gy >= P) continue;
        const float a0 = acc[rp][0], a1 = acc[rp][1], a2 = acc[rp][2], a3 = acc[rp][3];
        const float a4 = acc[rp][4], a5 = acc[rp][5], a6 = acc[rp][6], a7 = acc[rp][7];
        float best = a0, ba = fabsf(a0), t;
        t = fabsf(a1); if (t < ba) { ba = t; best = a1; }
        t = fabsf(a2); if (t < ba) { ba = t; best = a2; }
        t = fabsf(a3); if (t < ba) { ba = t; best = a3; }
        t = fabsf(a4); if (t < ba) { ba = t; best = a4; }
        t = fabsf(a5); if (t < ba) { ba = t; best = a5; }
        t = fabsf(a6); if (t < ba) { ba = t; best = a6; }
        t = fabsf(a7); if (t < ba) { ba = t; best = a7; }
        const float u = sU[r0 + rp + RAD][tx + RAD];
        dp[(size_t)gy * RS + gx] = __fadd_rn(u, best);
    }
}

// ---------------------------------------------------------------------------
// Crop interior of plane(s) back into HWC float32 output (z-batched)
// ---------------------------------------------------------------------------
__global__ void crop_kernel(const float* __restrict__ src, float* __restrict__ dst, int c0) {
    int idx = blockIdx.x * blockDim.x + threadIdx.x;
    int total = H * W;
    if (idx >= total) return;
    int c = c0 + blockIdx.z;
    const float* s = src + (size_t)blockIdx.z * PLANE;
    int y = idx / W;
    int x = idx - y * W;
    dst[((size_t)y * W + x) * C + c] = s[(size_t)(y + RAD) * RS + (x + RAD)];
}

extern "C" void kernel_launch(void* const* d_in, const int* in_sizes, int n_in,
                              void* d_out, int out_size, void* d_ws, size_t ws_size,
                              hipStream_t stream) {
    const float* img  = (const float*)d_in[0];
    const float* kern = (const float*)d_in[1];
    float* out = (float*)d_out;

    dim3 sblock(64, 4, 1);
    const int gxb = (P + BX - 1) / BX;   // 33
    const int gyb = (P + BY - 1) / BY;   // 129
    const int padg = (P * P + 255) / 256;
    const int crpg = (H * W + 255) / 256;

    if (ws_size >= (size_t)6 * PLANE * sizeof(float)) {
        // Batched: 3 channels per launch (b0/b1 = 3 planes each, 102 MB)
        float* b0 = (float*)d_ws;
        float* b1 = b0 + 3 * PLANE;
        pad_kernel<<<dim3(padg, 1, C), 256, 0, stream>>>(img, b0, 0);
        for (int i = 0; i < NITER; ++i) {
            const float* s = (i & 1) ? b1 : b0;
            float*       d = (i & 1) ? b0 : b1;
            step_kernel<<<dim3(gxb, gyb, C), sblock, 0, stream>>>(s, d, kern);
        }
        crop_kernel<<<dim3(crpg, 1, C), 256, 0, stream>>>(b0, out, 0);
    } else {
        // Fallback: per-channel loop, 2 planes (34 MB), same kernels with z=1
        float* b0 = (float*)d_ws;
        float* b1 = b0 + PLANE;
        for (int c = 0; c < C; ++c) {
            pad_kernel<<<dim3(padg, 1, 1), 256, 0, stream>>>(img, b0, c);
            for (int i = 0; i < NITER; ++i) {
                const float* s = (i & 1) ? b1 : b0;
                float*       d = (i & 1) ? b0 : b1;
                step_kernel<<<dim3(gxb, gyb, 1), sblock, 0, stream>>>(s, d, kern);
            }
            crop_kernel<<<dim3(crpg, 1, 1), 256, 0, stream>>>(b0, out, c);
        }
    }
}